// Round 1
// baseline (1176.266 us; speedup 1.0000x reference)
//
#include <hip/hip_runtime.h>
#include <cmath>
#include <cstring>

#ifndef M_PI
#define M_PI 3.14159265358979323846
#endif

// 32x32 SPD pipeline. 32768 matrices.
#define STRIDE 36                 // padded row stride (floats) for 256-thread mm slabs
#define SLAB   (32*STRIDE)        // 1152 floats = 4608 B (16B-aligned)
#define S33    33                 // padded stride for 1024-thread small kernels

// workspace float offsets
#define WS_GACC 0
#define WS_TACC 1024
#define WS_GS   2048
#define WS_GIS  3072
#define WS_WSQ  4096
#define WS_P    5120

struct Coef {
  float ic[4];   // Newton-inverse init: X0 = ic0*I + ic1*A + ic2*A^2 + ic3*A^3
  float a[12];   // q(V) monomial coeffs: atanh(w) ~ w * sum_m a[m] * (w^2)^m
};

// ---------------------------------------------------------------------------
// device helpers
// ---------------------------------------------------------------------------

// 256-thread 32x32 matmul: thread t owns row r=t>>3, cols c0..c0+3, c0=4*(t&7).
// Returns the 4 accumulated outputs; caller handles barriers/stores.
__device__ __forceinline__ float4 mmrow(const float* __restrict__ A,
                                        const float* __restrict__ B,
                                        int r, int c0) {
  float o0 = 0.f, o1 = 0.f, o2 = 0.f, o3 = 0.f;
  const float* Ar = A + r * STRIDE;
#pragma unroll
  for (int k4 = 0; k4 < 8; ++k4) {
    float4 a = *(const float4*)(Ar + 4 * k4);
    const float* Bp = B + 4 * k4 * STRIDE + c0;
    float4 b0 = *(const float4*)(Bp);
    float4 b1 = *(const float4*)(Bp + STRIDE);
    float4 b2 = *(const float4*)(Bp + 2 * STRIDE);
    float4 b3 = *(const float4*)(Bp + 3 * STRIDE);
    o0 = fmaf(a.x, b0.x, o0); o1 = fmaf(a.x, b0.y, o1); o2 = fmaf(a.x, b0.z, o2); o3 = fmaf(a.x, b0.w, o3);
    o0 = fmaf(a.y, b1.x, o0); o1 = fmaf(a.y, b1.y, o1); o2 = fmaf(a.y, b1.z, o2); o3 = fmaf(a.y, b1.w, o3);
    o0 = fmaf(a.z, b2.x, o0); o1 = fmaf(a.z, b2.y, o1); o2 = fmaf(a.z, b2.z, o2); o3 = fmaf(a.z, b2.w, o3);
    o0 = fmaf(a.w, b3.x, o0); o1 = fmaf(a.w, b3.y, o1); o2 = fmaf(a.w, b3.z, o2); o3 = fmaf(a.w, b3.w, o3);
  }
  return make_float4(o0, o1, o2, o3);
}

// 1024-thread 32x32 matmul element: thread (r,c) computes one element.
__device__ __forceinline__ float mm32(const float* A, const float* B, int r, int c) {
  float s = 0.f;
#pragma unroll
  for (int k = 0; k < 32; ++k) s = fmaf(A[r * S33 + k], B[k * S33 + c], s);
  return s;
}

// ---------------------------------------------------------------------------
// kernels
// ---------------------------------------------------------------------------

__global__ __launch_bounds__(256) void k_zero(float* __restrict__ ws) {
  int t = blockIdx.x * 256 + threadIdx.x;
  if (t < 2048) ws[t] = 0.f;  // g accumulator + t accumulator
}

// mean over matrices: thread handles one element e, a strided slice of matrices
__global__ __launch_bounds__(256) void k_mean(const float* __restrict__ X,
                                              float* __restrict__ ws,
                                              int nmat, int slices, float inv_nmat) {
  int gid = blockIdx.x * 256 + threadIdx.x;
  int e = gid & 1023;
  int s = gid >> 10;
  float sum = 0.f;
  for (int m = s; m < nmat; m += slices) sum += X[(size_t)m * 1024 + e];
  atomicAdd(ws + WS_GACC + e, sum * inv_nmat);
}

// single block: g -> gs,gis (coupled Newton-Schulz); weight -> sqrtm(weight)
__global__ __launch_bounds__(1024) void k_prep1(const float* __restrict__ Wt,
                                                float* __restrict__ ws) {
  __shared__ float A[32 * S33], Y[32 * S33], Z[32 * S33], T[32 * S33];
  __shared__ float red[32];
  __shared__ float csh;
  const int t = threadIdx.x, r = t >> 5, c = t & 31;
  const int i33 = r * S33 + c;
  const float dia = (r == c) ? 1.f : 0.f;

  // ---- part 1: mean g ----
  A[i33] = ws[WS_GACC + t];
  __syncthreads();
  if (t < 32) { float s = 0.f; for (int k = 0; k < 32; ++k) s += fabsf(A[t * S33 + k]); red[t] = s; }
  __syncthreads();
  if (t == 0) { float mx = 0.f; for (int k = 0; k < 32; ++k) mx = fmaxf(mx, red[k]); csh = mx; }
  __syncthreads();
  float cg = csh;
  Y[i33] = A[i33] / cg;
  Z[i33] = dia;
  __syncthreads();
  for (int it = 0; it < 10; ++it) {
    float m = mm32(Z, Y, r, c);
    __syncthreads();
    T[i33] = 0.5f * (3.f * dia - m);
    __syncthreads();
    float ny = mm32(Y, T, r, c);
    float nz = mm32(T, Z, r, c);
    __syncthreads();
    Y[i33] = ny; Z[i33] = nz;
    __syncthreads();
  }
  {
    float sc = sqrtf(cg);
    ws[WS_GS + t] = Y[i33] * sc;
    ws[WS_GIS + t] = Z[i33] / sc;
  }
  __syncthreads();

  // ---- part 2: sqrtm(weight) ----
  A[i33] = Wt[t];
  __syncthreads();
  if (t < 32) { float s = 0.f; for (int k = 0; k < 32; ++k) s += fabsf(A[t * S33 + k]); red[t] = s; }
  __syncthreads();
  if (t == 0) { float mx = 0.f; for (int k = 0; k < 32; ++k) mx = fmaxf(mx, red[k]); csh = mx; }
  __syncthreads();
  float cw = csh;
  Y[i33] = A[i33] / cw;
  Z[i33] = dia;
  __syncthreads();
  for (int it = 0; it < 16; ++it) {
    float m = mm32(Z, Y, r, c);
    __syncthreads();
    T[i33] = 0.5f * (3.f * dia - m);
    __syncthreads();
    float ny = mm32(Y, T, r, c);
    float nz = mm32(T, Z, r, c);
    __syncthreads();
    Y[i33] = ny; Z[i33] = nz;
    __syncthreads();
  }
  ws[WS_WSQ + t] = Y[i33] * sqrtf(cw);
}

// heavy pass: per matrix, S = gis*X*gis; logm(S) = 2*atanh(I - 2*(S+I)^-1); accumulate
__global__ __launch_bounds__(256) void k_log(const float* __restrict__ X,
                                             float* __restrict__ ws,
                                             int nmat, Coef cf) {
  __shared__ __align__(16) float lds[7 * SLAB];
  float* G   = lds;
  float* P0  = lds + SLAB;
  float* P1  = lds + 2 * SLAB;
  float* P2  = lds + 3 * SLAB;
  float* P3  = lds + 4 * SLAB;
  float* P4  = lds + 5 * SLAB;
  float* TAC = lds + 6 * SLAB;

  const int t = threadIdx.x;
  const int r = t >> 3;
  const int c0 = (t & 7) * 4;
  const int li = r * STRIDE + c0;

  {
    *(float4*)(G + li) = *(const float4*)(ws + WS_GIS + r * 32 + c0);
    *(float4*)(TAC + li) = make_float4(0.f, 0.f, 0.f, 0.f);
  }
  __syncthreads();

  const float d0 = (r == c0 + 0) ? 1.f : 0.f;
  const float d1 = (r == c0 + 1) ? 1.f : 0.f;
  const float d2 = (r == c0 + 2) ? 1.f : 0.f;
  const float d3 = (r == c0 + 3) ? 1.f : 0.f;

  for (int m = blockIdx.x; m < nmat; m += gridDim.x) {
    // X -> P0
    *(float4*)(P0 + li) = *(const float4*)(X + (size_t)m * 1024 + r * 32 + c0);
    __syncthreads();
    // P1 = gis * X
    float4 acc = mmrow(G, P0, r, c0);
    *(float4*)(P1 + li) = acc;
    __syncthreads();
    // P2 = (gis*X)*gis + I  == A = S + I
    acc = mmrow(P1, G, r, c0);
    acc.x += d0; acc.y += d1; acc.z += d2; acc.w += d3;
    *(float4*)(P2 + li) = acc;
    __syncthreads();
    // Newton-inverse init: X0 = ((ic3*A + ic2*I)*A + ic1*I)*A + ic0*I  (into P0)
    {
      float4 a4 = *(const float4*)(P2 + li);
      float4 v;
      v.x = cf.ic[3] * a4.x + cf.ic[2] * d0;
      v.y = cf.ic[3] * a4.y + cf.ic[2] * d1;
      v.z = cf.ic[3] * a4.z + cf.ic[2] * d2;
      v.w = cf.ic[3] * a4.w + cf.ic[2] * d3;
      *(float4*)(P0 + li) = v;
      __syncthreads();
      acc = mmrow(P0, P2, r, c0);
      acc.x += cf.ic[1] * d0; acc.y += cf.ic[1] * d1; acc.z += cf.ic[1] * d2; acc.w += cf.ic[1] * d3;
      __syncthreads();
      *(float4*)(P0 + li) = acc;
      __syncthreads();
      acc = mmrow(P0, P2, r, c0);
      acc.x += cf.ic[0] * d0; acc.y += cf.ic[0] * d1; acc.z += cf.ic[0] * d2; acc.w += cf.ic[0] * d3;
      __syncthreads();
      *(float4*)(P0 + li) = acc;
      __syncthreads();
    }
    // 3x Newton: Xk+1 = 2*Xk - Xk*(A*Xk)
#pragma unroll 1
    for (int it = 0; it < 3; ++it) {
      acc = mmrow(P2, P0, r, c0);      // M = A*X
      *(float4*)(P1 + li) = acc;
      __syncthreads();
      acc = mmrow(P0, P1, r, c0);      // X*M
      float4 x4 = *(const float4*)(P0 + li);
      __syncthreads();
      acc.x = 2.f * x4.x - acc.x;
      acc.y = 2.f * x4.y - acc.y;
      acc.z = 2.f * x4.z - acc.z;
      acc.w = 2.f * x4.w - acc.w;
      *(float4*)(P0 + li) = acc;       // P0 = R ~= (S+I)^-1
      __syncthreads();
    }
    // V = W^2 = (I-2R)^2 = I - 4R + 4R^2 : P1 = R^2; P2 = V
    acc = mmrow(P0, P0, r, c0);
    *(float4*)(P1 + li) = acc;
    __syncthreads();
    {
      float4 x4 = *(const float4*)(P0 + li);
      float4 s4 = *(const float4*)(P1 + li);
      float4 v;
      v.x = d0 - 4.f * x4.x + 4.f * s4.x;
      v.y = d1 - 4.f * x4.y + 4.f * s4.y;
      v.z = d2 - 4.f * x4.z + 4.f * s4.z;
      v.w = d3 - 4.f * x4.w + 4.f * s4.w;
      *(float4*)(P2 + li) = v;
      __syncthreads();
    }
    // P3 = V^2, P4 = V^3
    acc = mmrow(P2, P2, r, c0);
    *(float4*)(P3 + li) = acc;
    __syncthreads();
    acc = mmrow(P3, P2, r, c0);
    *(float4*)(P4 + li) = acc;
    __syncthreads();
    // q(V), Paterson-Stockmeyer s=3: acc-slab P1 = Q3 = a9*I + a10*V + a11*V^2
    {
      float4 v4 = *(const float4*)(P2 + li);
      float4 w4 = *(const float4*)(P3 + li);
      float4 q;
      q.x = cf.a[9] * d0 + cf.a[10] * v4.x + cf.a[11] * w4.x;
      q.y = cf.a[9] * d1 + cf.a[10] * v4.y + cf.a[11] * w4.y;
      q.z = cf.a[9] * d2 + cf.a[10] * v4.z + cf.a[11] * w4.z;
      q.w = cf.a[9] * d3 + cf.a[10] * v4.w + cf.a[11] * w4.w;
      *(float4*)(P1 + li) = q;
      __syncthreads();
    }
#pragma unroll 1
    for (int B = 2; B >= 0; --B) {
      acc = mmrow(P1, P4, r, c0);      // acc*V^3
      float4 v4 = *(const float4*)(P2 + li);
      float4 w4 = *(const float4*)(P3 + li);
      __syncthreads();
      float4 q;
      q.x = acc.x + cf.a[3 * B] * d0 + cf.a[3 * B + 1] * v4.x + cf.a[3 * B + 2] * w4.x;
      q.y = acc.y + cf.a[3 * B] * d1 + cf.a[3 * B + 1] * v4.y + cf.a[3 * B + 2] * w4.y;
      q.z = acc.z + cf.a[3 * B] * d2 + cf.a[3 * B + 1] * v4.z + cf.a[3 * B + 2] * w4.z;
      q.w = acc.w + cf.a[3 * B] * d3 + cf.a[3 * B + 1] * v4.w + cf.a[3 * B + 2] * w4.w;
      *(float4*)(P1 + li) = q;
      __syncthreads();
    }
    // logm(S) = 2*W*q = 2*q - 4*R*q ; accumulate into TAC
    acc = mmrow(P0, P1, r, c0);        // R*q
    {
      float4 q4 = *(const float4*)(P1 + li);
      float4 tc = *(float4*)(TAC + li);
      tc.x += 2.f * q4.x - 4.f * acc.x;
      tc.y += 2.f * q4.y - 4.f * acc.y;
      tc.z += 2.f * q4.z - 4.f * acc.z;
      tc.w += 2.f * q4.w - 4.f * acc.w;
      *(float4*)(TAC + li) = tc;
    }
    __syncthreads();
  }
  atomicAdd(ws + WS_TACC + r * 32 + c0 + 0, TAC[li + 0]);
  atomicAdd(ws + WS_TACC + r * 32 + c0 + 1, TAC[li + 1]);
  atomicAdd(ws + WS_TACC + r * 32 + c0 + 2, TAC[li + 2]);
  atomicAdd(ws + WS_TACC + r * 32 + c0 + 3, TAC[li + 3]);
}

// single block: t -> expm -> g' -> invsqrtm -> P = wsq * gis'
__global__ __launch_bounds__(1024) void k_prep2(float* __restrict__ ws, float inv_nmat) {
  __shared__ float U[32 * S33], E[32 * S33], A[32 * S33], T[32 * S33], M[32 * S33];
  __shared__ float red[32];
  __shared__ float csh;
  const int t = threadIdx.x, r = t >> 5, c = t & 31;
  const int i33 = r * S33 + c;
  const float dia = (r == c) ? 1.f : 0.f;

  U[i33] = ws[WS_TACC + t] * inv_nmat * 0.125f;  // t/8
  __syncthreads();
  // E = Taylor-6 exp(U)
  E[i33] = dia * (1.f / 720.f);
  __syncthreads();
  const float invf[6] = {1.f, 1.f, 0.5f, 1.f / 6.f, 1.f / 24.f, 1.f / 120.f};
#pragma unroll 1
  for (int k = 5; k >= 0; --k) {
    float m = mm32(E, U, r, c);
    __syncthreads();
    E[i33] = m + invf[k] * dia;
    __syncthreads();
  }
#pragma unroll 1
  for (int sq = 0; sq < 3; ++sq) {   // E <- E^2 three times: exp(t)
    float m = mm32(E, E, r, c);
    __syncthreads();
    E[i33] = m;
    __syncthreads();
  }
  // A = sym(gs * E * gs)
  M[i33] = ws[WS_GS + t];
  __syncthreads();
  float m1 = mm32(M, E, r, c);
  __syncthreads();
  T[i33] = m1;
  __syncthreads();
  float m2 = mm32(T, M, r, c);
  __syncthreads();
  U[i33] = m2;
  __syncthreads();
  A[i33] = 0.5f * (U[i33] + U[c * S33 + r]);
  __syncthreads();
  // NS invsqrt(A)
  if (t < 32) { float s = 0.f; for (int k = 0; k < 32; ++k) s += fabsf(A[t * S33 + k]); red[t] = s; }
  __syncthreads();
  if (t == 0) { float mx = 0.f; for (int k = 0; k < 32; ++k) mx = fmaxf(mx, red[k]); csh = mx; }
  __syncthreads();
  float cg = csh;
  T[i33] = A[i33] / cg;   // Y
  M[i33] = dia;           // Z
  __syncthreads();
#pragma unroll 1
  for (int it = 0; it < 12; ++it) {
    float mz = mm32(M, T, r, c);          // Z*Y
    __syncthreads();
    E[i33] = 0.5f * (3.f * dia - mz);
    __syncthreads();
    float ny = mm32(T, E, r, c);
    float nz = mm32(E, M, r, c);
    __syncthreads();
    T[i33] = ny; M[i33] = nz;
    __syncthreads();
  }
  // P = wsq * gis'  (gis' = M / sqrt(cg))
  A[i33] = ws[WS_WSQ + t];
  __syncthreads();
  float p = mm32(A, M, r, c);
  ws[WS_P + t] = p / sqrtf(cg);
}

// final congruence: out = P * X * P^T
__global__ __launch_bounds__(256) void k_final(const float* __restrict__ X,
                                               const float* __restrict__ ws,
                                               float* __restrict__ out, int nmat) {
  __shared__ __align__(16) float lds[4 * SLAB];
  float* Pm = lds;
  float* PT = lds + SLAB;
  float* Xs = lds + 2 * SLAB;
  float* Ms = lds + 3 * SLAB;
  const int t = threadIdx.x, r = t >> 3, c0 = (t & 7) * 4;
  const int li = r * STRIDE + c0;
  {
    float4 p4 = *(const float4*)(ws + WS_P + r * 32 + c0);
    *(float4*)(Pm + li) = p4;
    PT[(c0 + 0) * STRIDE + r] = p4.x;
    PT[(c0 + 1) * STRIDE + r] = p4.y;
    PT[(c0 + 2) * STRIDE + r] = p4.z;
    PT[(c0 + 3) * STRIDE + r] = p4.w;
  }
  __syncthreads();
  for (int m = blockIdx.x; m < nmat; m += gridDim.x) {
    *(float4*)(Xs + li) = *(const float4*)(X + (size_t)m * 1024 + r * 32 + c0);
    __syncthreads();
    float4 a = mmrow(Pm, Xs, r, c0);
    *(float4*)(Ms + li) = a;
    __syncthreads();
    float4 o = mmrow(Ms, PT, r, c0);
    *(float4*)(out + (size_t)m * 1024 + r * 32 + c0) = o;
    __syncthreads();
  }
}

// ---------------------------------------------------------------------------
// host: coefficient construction (deterministic, double precision)
// ---------------------------------------------------------------------------
static Coef make_coefs() {
  Coef cf;
  // cubic Chebyshev projection of 1/x on [lo,hi] -> monomial in x
  {
    const double lo = 1.05, hi = 8.0;
    const int M = 128, D = 3;
    double ch[4] = {0, 0, 0, 0};
    for (int i = 0; i < M; ++i) {
      double th = M_PI * (i + 0.5) / M, u = cos(th);
      double x = 0.5 * ((hi + lo) + (hi - lo) * u);
      double f = 1.0 / x;
      for (int k = 0; k <= D; ++k) ch[k] += f * cos(k * th);
    }
    ch[0] /= M;
    for (int k = 1; k <= D; ++k) ch[k] *= 2.0 / M;
    // T_k monomials in u
    double tm[4][4] = {{1, 0, 0, 0}, {0, 1, 0, 0}, {-1, 0, 2, 0}, {0, -3, 0, 4}};
    double au[4] = {0, 0, 0, 0};
    for (int k = 0; k <= D; ++k)
      for (int j = 0; j <= k; ++j) au[j] += ch[k] * tm[k][j];
    double al = 2.0 / (hi - lo), be = -(hi + lo) / (hi - lo);
    double dx[4] = {0, 0, 0, 0};
    dx[0] += au[0];
    dx[0] += au[1] * be;           dx[1] += au[1] * al;
    dx[0] += au[2] * be * be;      dx[1] += au[2] * 2 * al * be;      dx[2] += au[2] * al * al;
    dx[0] += au[3] * be * be * be; dx[1] += au[3] * 3 * al * be * be; dx[2] += au[3] * 3 * al * al * be;
    dx[3] += au[3] * al * al * al;
    for (int k = 0; k < 4; ++k) cf.ic[k] = (float)dx[k];
  }
  // odd Chebyshev fit of atanh(w) on [-R,R], degree 23 -> monomial coeffs in w^2
  {
    const double R = 0.860;
    const int D = 23, M = 256;
    double ch[24]; for (int k = 0; k < 24; ++k) ch[k] = 0;
    for (int i = 0; i < M; ++i) {
      double th = M_PI * (i + 0.5) / M, u = cos(th);
      double f = atanh(R * u);
      for (int k = 1; k <= D; k += 2) ch[k] += f * cos(k * th);
    }
    for (int k = 1; k <= D; k += 2) ch[k] *= 2.0 / M;
    static double tmn[24][24];
    memset(tmn, 0, sizeof(tmn));
    tmn[0][0] = 1; tmn[1][1] = 1;
    for (int k = 2; k <= D; ++k)
      for (int j = 0; j <= k; ++j) {
        double v = -tmn[k - 2][j];
        if (j > 0) v += 2 * tmn[k - 1][j - 1];
        tmn[k][j] = v;
      }
    double am[24]; for (int j = 0; j < 24; ++j) am[j] = 0;
    for (int k = 1; k <= D; k += 2)
      for (int j = 0; j <= k; ++j) am[j] += ch[k] * tmn[k][j];
    for (int m = 0; m < 12; ++m) cf.a[m] = (float)(am[2 * m + 1] / pow(R, 2 * m + 1));
  }
  return cf;
}

// ---------------------------------------------------------------------------
extern "C" void kernel_launch(void* const* d_in, const int* in_sizes, int n_in,
                              void* d_out, int out_size, void* d_ws, size_t ws_size,
                              hipStream_t stream) {
  (void)n_in; (void)out_size; (void)ws_size;
  const float* X = (const float*)d_in[0];
  const float* Wt = (const float*)d_in[1];
  float* out = (float*)d_out;
  float* ws = (float*)d_ws;
  const int nmat = in_sizes[0] / 1024;          // 32768
  const float inv_nmat = 1.0f / (float)nmat;

  Coef cf = make_coefs();  // deterministic host math, baked into captured args

  k_zero<<<dim3(8), dim3(256), 0, stream>>>(ws);
  k_mean<<<dim3(1024), dim3(256), 0, stream>>>(X, ws, nmat, 256, inv_nmat);
  k_prep1<<<dim3(1), dim3(1024), 0, stream>>>(Wt, ws);
  k_log<<<dim3(4096), dim3(256), 0, stream>>>(X, ws, nmat, cf);
  k_prep2<<<dim3(1), dim3(1024), 0, stream>>>(ws, inv_nmat);
  k_final<<<dim3(2048), dim3(256), 0, stream>>>(X, ws, out, nmat);
}

// Round 7
// 638.907 us; speedup vs baseline: 1.8411x; 1.8411x over previous
//
#include <hip/hip_runtime.h>
#include <hip/hip_bf16.h>
#include <cmath>
#include <cstring>

#ifndef M_PI
#define M_PI 3.14159265358979323846
#endif

typedef __attribute__((ext_vector_type(16))) float f32x16;
typedef __attribute__((ext_vector_type(4))) unsigned int uint4v;
typedef unsigned long long ull;

#define S33 33

// workspace float offsets
#define WS_GACC 0
#define WS_TACC 1024
#define WS_GS   2048
#define WS_GIS  3072
#define WS_WSQ  4096
#define WS_P    5120

// per-wave LDS staging: transposed split-bf16 planes, row stride 40 ushorts
// (80 B rows -> 16B-aligned b128 reads; bank step 20 -> ~4-way conflicts max)
#define STG_ROW 40
#define STG_PLANE (32 * STG_ROW)   // 1280 ushorts
#define STG_WAVE (2 * STG_PLANE)   // hi plane + lo plane

struct Coef {
  float ic[4];   // Newton-inverse init: X0 = ic0*I + ic1*A + ic2*A^2 + ic3*A^3
  float a[12];   // q(V) monomial coeffs: atanh(w) ~ w * sum_m a[m] * (w^2)^m
};

struct Frag { uint4v h0, h1, l0, l1; };  // split bf16 frags; h0/h1 = K-chunks

// ---------------------------------------------------------------------------
// bf16 helpers (official HIP API; rounding mode of hi irrelevant: lo captures
// the remainder, split accuracy ~2^-16 relative either way)
// ---------------------------------------------------------------------------
__device__ __forceinline__ unsigned short f2bf(float x) {
  __hip_bfloat16 b = __float2bfloat16(x);
  return __builtin_bit_cast(unsigned short, b);
}
__device__ __forceinline__ float bf2f(unsigned short s) {
  unsigned u = ((unsigned)s) << 16;
  return __builtin_bit_cast(float, u);
}
__device__ __forceinline__ void split4(float x0, float x1, float x2, float x3,
                                       ull& hw, ull& lw) {
  unsigned short h0 = f2bf(x0), h1 = f2bf(x1), h2 = f2bf(x2), h3 = f2bf(x3);
  unsigned short q0 = f2bf(x0 - bf2f(h0)), q1 = f2bf(x1 - bf2f(h1));
  unsigned short q2 = f2bf(x2 - bf2f(h2)), q3 = f2bf(x3 - bf2f(h3));
  hw = (ull)h0 | ((ull)h1 << 16) | ((ull)h2 << 32) | ((ull)h3 << 48);
  lw = (ull)q0 | ((ull)q1 << 16) | ((ull)q2 << 32) | ((ull)q3 << 48);
}
__device__ __forceinline__ void zero16(f32x16& c) {
#pragma unroll
  for (int r = 0; r < 16; ++r) c[r] = 0.f;
}

// ---------------------------------------------------------------------------
// MFMA: acc += A*B with split-bf16 3-product emulation of fp32.
// Inline asm; compiler does NOT model MFMA hazards, so guard manually:
//   pre:  s_nop 3 (VALU write -> MFMA read operand needs 2)
//   post: 3x s_nop 7 = 24 cyc (16-pass MFMA write -> VALU/LDS read needs ~18)
// MFMA->MFMA same-acc chaining needs no waits (same pass count).
// ---------------------------------------------------------------------------
__device__ __forceinline__ void matmul(f32x16& acc, Frag A, Frag B) {
  asm volatile("s_nop 3"
               : "+v"(acc), "+v"(A.h0), "+v"(A.h1), "+v"(A.l0), "+v"(A.l1),
                 "+v"(B.h0), "+v"(B.h1), "+v"(B.l0), "+v"(B.l1));
  asm("v_mfma_f32_32x32x16_bf16 %0, %1, %2, %0" : "+v"(acc) : "v"(A.h0), "v"(B.h0));
  asm("v_mfma_f32_32x32x16_bf16 %0, %1, %2, %0" : "+v"(acc) : "v"(A.h1), "v"(B.h1));
  asm("v_mfma_f32_32x32x16_bf16 %0, %1, %2, %0" : "+v"(acc) : "v"(A.h0), "v"(B.l0));
  asm("v_mfma_f32_32x32x16_bf16 %0, %1, %2, %0" : "+v"(acc) : "v"(A.h1), "v"(B.l1));
  asm("v_mfma_f32_32x32x16_bf16 %0, %1, %2, %0" : "+v"(acc) : "v"(A.l0), "v"(B.h0));
  asm("v_mfma_f32_32x32x16_bf16 %0, %1, %2, %0" : "+v"(acc) : "v"(A.l1), "v"(B.h1));
  asm volatile("s_nop 7\n\ts_nop 7\n\ts_nop 7" : "+v"(acc));
}

// ---------------------------------------------------------------------------
// C-layout f32 regs -> B-frag (and A-frag when the matrix is symmetric).
// Store transposed (stg[col][row]) as split bf16; wave-local, no __syncthreads.
// C/D layout (HW-verified): col = lane&31, row = (reg&3)+8*(reg>>2)+4*(lane>>5).
// A/B frags use k-map sigma(hl,e): chunk0 k=8*hl+e, chunk1 k=16+8*hl+e -- the
// natural CDNA layout; and any bijective sigma cancels when BOTH operands use
// it (A/B are HW mirrors).
// ---------------------------------------------------------------------------
__device__ __forceinline__ Frag conv_c(const f32x16& c, unsigned short* sw,
                                       int j, int hl) {
#pragma unroll
  for (int g = 0; g < 4; ++g) {
    ull hw, lw;
    split4(c[4 * g + 0], c[4 * g + 1], c[4 * g + 2], c[4 * g + 3], hw, lw);
    const int base = 8 * g + 4 * hl;           // rows covered by regs 4g..4g+3
    *(ull*)(sw + j * STG_ROW + base) = hw;
    *(ull*)(sw + STG_PLANE + j * STG_ROW + base) = lw;
  }
  asm volatile("s_waitcnt lgkmcnt(0)" ::: "memory");
  Frag f;
  const int k0 = 8 * hl;
  f.h0 = *(const uint4v*)(sw + j * STG_ROW + k0);
  f.h1 = *(const uint4v*)(sw + j * STG_ROW + 16 + k0);
  f.l0 = *(const uint4v*)(sw + STG_PLANE + j * STG_ROW + k0);
  f.l1 = *(const uint4v*)(sw + STG_PLANE + j * STG_ROW + 16 + k0);
  asm volatile("s_waitcnt lgkmcnt(0)" ::: "memory");
  return f;
}

// Row-major 32x32 f32 matrix -> A-frag of M (= B-frag of M^T).
__device__ __forceinline__ Frag load_frag(const float* __restrict__ M,
                                          int j, int hl) {
  const float* p = M + j * 32 + 8 * hl;
  float4 a0 = *(const float4*)(p);
  float4 a1 = *(const float4*)(p + 4);
  float4 b0 = *(const float4*)(p + 16);
  float4 b1 = *(const float4*)(p + 20);
  Frag f; ull hw, lw;
  split4(a0.x, a0.y, a0.z, a0.w, hw, lw);
  f.h0.x = (unsigned)hw; f.h0.y = (unsigned)(hw >> 32);
  f.l0.x = (unsigned)lw; f.l0.y = (unsigned)(lw >> 32);
  split4(a1.x, a1.y, a1.z, a1.w, hw, lw);
  f.h0.z = (unsigned)hw; f.h0.w = (unsigned)(hw >> 32);
  f.l0.z = (unsigned)lw; f.l0.w = (unsigned)(lw >> 32);
  split4(b0.x, b0.y, b0.z, b0.w, hw, lw);
  f.h1.x = (unsigned)hw; f.h1.y = (unsigned)(hw >> 32);
  f.l1.x = (unsigned)lw; f.l1.y = (unsigned)(lw >> 32);
  split4(b1.x, b1.y, b1.z, b1.w, hw, lw);
  f.h1.z = (unsigned)hw; f.h1.w = (unsigned)(hw >> 32);
  f.l1.z = (unsigned)lw; f.l1.w = (unsigned)(lw >> 32);
  return f;
}

// ---------------------------------------------------------------------------
// small-kernel helpers (1024-thread prep kernels)
// ---------------------------------------------------------------------------
__device__ __forceinline__ float mm32(const float* A, const float* B, int r, int c) {
  float s = 0.f;
#pragma unroll
  for (int k = 0; k < 32; ++k) s = fmaf(A[r * S33 + k], B[k * S33 + c], s);
  return s;
}

__global__ __launch_bounds__(256) void k_zero(float* __restrict__ ws) {
  int t = blockIdx.x * 256 + threadIdx.x;
  if (t < 2048) ws[t] = 0.f;
}

__global__ __launch_bounds__(256) void k_mean(const float* __restrict__ X,
                                              float* __restrict__ ws,
                                              int nmat, int slices, float inv_nmat) {
  int gid = blockIdx.x * 256 + threadIdx.x;
  int e = gid & 1023;
  int s = gid >> 10;
  float sum = 0.f;
  for (int m = s; m < nmat; m += slices) sum += X[(size_t)m * 1024 + e];
  atomicAdd(ws + WS_GACC + e, sum * inv_nmat);
}

__global__ __launch_bounds__(1024) void k_prep1(const float* __restrict__ Wt,
                                                float* __restrict__ ws) {
  __shared__ float A[32 * S33], Y[32 * S33], Z[32 * S33], T[32 * S33];
  __shared__ float red[32];
  __shared__ float csh;
  const int t = threadIdx.x, r = t >> 5, c = t & 31;
  const int i33 = r * S33 + c;
  const float dia = (r == c) ? 1.f : 0.f;

  A[i33] = ws[WS_GACC + t];
  __syncthreads();
  if (t < 32) { float s = 0.f; for (int k = 0; k < 32; ++k) s += fabsf(A[t * S33 + k]); red[t] = s; }
  __syncthreads();
  if (t == 0) { float mx = 0.f; for (int k = 0; k < 32; ++k) mx = fmaxf(mx, red[k]); csh = mx; }
  __syncthreads();
  float cg = csh;
  Y[i33] = A[i33] / cg;
  Z[i33] = dia;
  __syncthreads();
  for (int it = 0; it < 10; ++it) {
    float m = mm32(Z, Y, r, c);
    __syncthreads();
    T[i33] = 0.5f * (3.f * dia - m);
    __syncthreads();
    float ny = mm32(Y, T, r, c);
    float nz = mm32(T, Z, r, c);
    __syncthreads();
    Y[i33] = ny; Z[i33] = nz;
    __syncthreads();
  }
  {
    float sc = sqrtf(cg);
    ws[WS_GS + t] = Y[i33] * sc;
    ws[WS_GIS + t] = Z[i33] / sc;
  }
  __syncthreads();

  A[i33] = Wt[t];
  __syncthreads();
  if (t < 32) { float s = 0.f; for (int k = 0; k < 32; ++k) s += fabsf(A[t * S33 + k]); red[t] = s; }
  __syncthreads();
  if (t == 0) { float mx = 0.f; for (int k = 0; k < 32; ++k) mx = fmaxf(mx, red[k]); csh = mx; }
  __syncthreads();
  float cw = csh;
  Y[i33] = A[i33] / cw;
  Z[i33] = dia;
  __syncthreads();
  for (int it = 0; it < 16; ++it) {
    float m = mm32(Z, Y, r, c);
    __syncthreads();
    T[i33] = 0.5f * (3.f * dia - m);
    __syncthreads();
    float ny = mm32(Y, T, r, c);
    float nz = mm32(T, Z, r, c);
    __syncthreads();
    Y[i33] = ny; Z[i33] = nz;
    __syncthreads();
  }
  ws[WS_WSQ + t] = Y[i33] * sqrtf(cw);
}

// ---------------------------------------------------------------------------
// heavy pass: per-wave matrix; logm(S) = 2*atanh(I - 2*(S+I)^-1) via MFMA.
// All chain intermediates are symmetric polynomials in A=S+I, so conv_c frags
// are valid as both A- and B-operands. No __syncthreads in the hot loop.
// ---------------------------------------------------------------------------
__global__ __launch_bounds__(256) void k_log(const float* __restrict__ X,
                                             float* __restrict__ ws,
                                             int nmat, int totwaves, Coef cf) {
  __shared__ __align__(16) unsigned short stg[4 * STG_WAVE];
  const int lane = threadIdx.x & 63;
  const int wv = threadIdx.x >> 6;
  const int j = lane & 31, hl = lane >> 5;
  unsigned short* sw = stg + wv * STG_WAVE;

  f32x16 dvec;   // identity matrix in C-layout
#pragma unroll
  for (int r = 0; r < 16; ++r)
    dvec[r] = (((r & 3) + 8 * (r >> 2) + 4 * hl) == j) ? 1.f : 0.f;

  Frag fgis = load_frag(ws + WS_GIS, j, hl);   // gis symmetric: A- and B-frag

  f32x16 tacc; zero16(tacc);

  const int wid = blockIdx.x * 4 + wv;
  const int per = (nmat + totwaves - 1) / totwaves;
  const int m0 = wid * per;
  const int m1 = (m0 + per < nmat) ? (m0 + per) : nmat;

#pragma unroll 1
  for (int m = m0; m < m1; ++m) {
    Frag fX = load_frag(X + (size_t)m * 1024, j, hl);
    f32x16 c;
    // c1 = X * gis
    zero16(c); matmul(c, fX, fgis);
    Frag f1 = conv_c(c, sw, j, hl);
    // a = gis * c1 + I  (= S + I, symmetric)
    c = dvec;
    matmul(c, fgis, f1);
    f32x16 am = c;
    Frag fA = conv_c(c, sw, j, hl);
    // Newton-inverse init: X0 = ((ic3*A + ic2 I) A + ic1 I) A + ic0 I
    f32x16 t;
#pragma unroll
    for (int r = 0; r < 16; ++r) t[r] = cf.ic[3] * am[r] + cf.ic[2] * dvec[r];
    Frag ft = conv_c(t, sw, j, hl);
#pragma unroll
    for (int r = 0; r < 16; ++r) c[r] = cf.ic[1] * dvec[r];
    matmul(c, fA, ft);
    ft = conv_c(c, sw, j, hl);
#pragma unroll
    for (int r = 0; r < 16; ++r) c[r] = cf.ic[0] * dvec[r];
    matmul(c, fA, ft);
    f32x16 xk = c;
    // Newton x3: Xk+1 = 2Xk - Xk*(A*Xk)
#pragma unroll 1
    for (int it = 0; it < 3; ++it) {
      Frag fx = conv_c(xk, sw, j, hl);
      zero16(c); matmul(c, fA, fx);          // M = A*Xk
      Frag fm = conv_c(c, sw, j, hl);
      zero16(c); matmul(c, fx, fm);          // Xk*M
#pragma unroll
      for (int r = 0; r < 16; ++r) xk[r] = 2.f * xk[r] - c[r];
    }
    // R = xk ~= (S+I)^-1 ; V = W^2 = I - 4R + 4R^2
    Frag fR = conv_c(xk, sw, j, hl);
    zero16(c); matmul(c, fR, fR);
    f32x16 v;
#pragma unroll
    for (int r = 0; r < 16; ++r) v[r] = dvec[r] - 4.f * xk[r] + 4.f * c[r];
    Frag fV = conv_c(v, sw, j, hl);
    zero16(c); matmul(c, fV, fV);
    f32x16 v2 = c;
    Frag fV2 = conv_c(v2, sw, j, hl);
    zero16(c); matmul(c, fV, fV2);           // V^3
    Frag fV3 = conv_c(c, sw, j, hl);
    // Paterson-Stockmeyer q(V), s=3
    f32x16 q;
#pragma unroll
    for (int r = 0; r < 16; ++r)
      q[r] = cf.a[9] * dvec[r] + cf.a[10] * v[r] + cf.a[11] * v2[r];
#pragma unroll 1
    for (int B = 2; B >= 0; --B) {
      Frag fq = conv_c(q, sw, j, hl);
#pragma unroll
      for (int r = 0; r < 16; ++r)
        c[r] = cf.a[3 * B] * dvec[r] + cf.a[3 * B + 1] * v[r] + cf.a[3 * B + 2] * v2[r];
      matmul(c, fq, fV3);
      q = c;
    }
    // L = 2q - 4 R*q ; accumulate
    Frag fq = conv_c(q, sw, j, hl);
    zero16(c); matmul(c, fR, fq);
#pragma unroll
    for (int r = 0; r < 16; ++r) tacc[r] += 2.f * q[r] - 4.f * c[r];
  }

  // block reduce (LDS) then global atomics
  __syncthreads();
  float* red = (float*)stg;
  for (int i = threadIdx.x; i < 1024; i += 256) red[i] = 0.f;
  __syncthreads();
#pragma unroll
  for (int r = 0; r < 16; ++r) {
    int row = (r & 3) + 8 * (r >> 2) + 4 * hl;
    atomicAdd(red + row * 32 + j, tacc[r]);
  }
  __syncthreads();
  for (int i = threadIdx.x; i < 1024; i += 256)
    atomicAdd(ws + WS_TACC + i, red[i]);
}

// single block: t -> expm -> g' -> invsqrtm -> P = wsq * gis'
__global__ __launch_bounds__(1024) void k_prep2(float* __restrict__ ws, float inv_nmat) {
  __shared__ float U[32 * S33], E[32 * S33], A[32 * S33], T[32 * S33], M[32 * S33];
  __shared__ float red[32];
  __shared__ float csh;
  const int t = threadIdx.x, r = t >> 5, c = t & 31;
  const int i33 = r * S33 + c;
  const float dia = (r == c) ? 1.f : 0.f;

  U[i33] = ws[WS_TACC + t] * inv_nmat * 0.125f;
  __syncthreads();
  E[i33] = dia * (1.f / 720.f);
  __syncthreads();
  const float invf[6] = {1.f, 1.f, 0.5f, 1.f / 6.f, 1.f / 24.f, 1.f / 120.f};
#pragma unroll 1
  for (int k = 5; k >= 0; --k) {
    float m = mm32(E, U, r, c);
    __syncthreads();
    E[i33] = m + invf[k] * dia;
    __syncthreads();
  }
#pragma unroll 1
  for (int sq = 0; sq < 3; ++sq) {
    float m = mm32(E, E, r, c);
    __syncthreads();
    E[i33] = m;
    __syncthreads();
  }
  M[i33] = ws[WS_GS + t];
  __syncthreads();
  float m1 = mm32(M, E, r, c);
  __syncthreads();
  T[i33] = m1;
  __syncthreads();
  float m2 = mm32(T, M, r, c);
  __syncthreads();
  U[i33] = m2;
  __syncthreads();
  A[i33] = 0.5f * (U[i33] + U[c * S33 + r]);
  __syncthreads();
  if (t < 32) { float s = 0.f; for (int k = 0; k < 32; ++k) s += fabsf(A[t * S33 + k]); red[t] = s; }
  __syncthreads();
  if (t == 0) { float mx = 0.f; for (int k = 0; k < 32; ++k) mx = fmaxf(mx, red[k]); csh = mx; }
  __syncthreads();
  float cg = csh;
  T[i33] = A[i33] / cg;
  M[i33] = dia;
  __syncthreads();
#pragma unroll 1
  for (int it = 0; it < 12; ++it) {
    float mz = mm32(M, T, r, c);
    __syncthreads();
    E[i33] = 0.5f * (3.f * dia - mz);
    __syncthreads();
    float ny = mm32(T, E, r, c);
    float nz = mm32(E, M, r, c);
    __syncthreads();
    T[i33] = ny; M[i33] = nz;
    __syncthreads();
  }
  A[i33] = ws[WS_WSQ + t];
  __syncthreads();
  float p = mm32(A, M, r, c);
  ws[WS_P + t] = p / sqrtf(cg);
}

// final congruence: out = P * (X * P^T) via MFMA, per-wave matrices
__global__ __launch_bounds__(256) void k_final(const float* __restrict__ X,
                                               const float* __restrict__ ws,
                                               float* __restrict__ out,
                                               int nmat, int totwaves) {
  __shared__ __align__(16) unsigned short stg[4 * STG_WAVE];
  const int lane = threadIdx.x & 63, wv = threadIdx.x >> 6;
  const int j = lane & 31, hl = lane >> 5;
  unsigned short* sw = stg + wv * STG_WAVE;
  Frag fP = load_frag(ws + WS_P, j, hl);     // A-frag of P; B-frag of P^T
  const int wid = blockIdx.x * 4 + wv;
  const int per = (nmat + totwaves - 1) / totwaves;
  const int m0 = wid * per;
  const int m1 = (m0 + per < nmat) ? (m0 + per) : nmat;
#pragma unroll 1
  for (int m = m0; m < m1; ++m) {
    Frag fX = load_frag(X + (size_t)m * 1024, j, hl);
    f32x16 c; zero16(c);
    matmul(c, fX, fP);                        // C1 = X * P^T
    Frag f1 = conv_c(c, sw, j, hl);
    zero16(c);
    matmul(c, fP, f1);                        // out = P * C1
    float* op = out + (size_t)m * 1024;
#pragma unroll
    for (int r = 0; r < 16; ++r) {
      int row = (r & 3) + 8 * (r >> 2) + 4 * hl;
      op[row * 32 + j] = c[r];
    }
  }
}

// ---------------------------------------------------------------------------
// host: coefficient construction (deterministic, double precision)
// ---------------------------------------------------------------------------
static Coef make_coefs() {
  Coef cf;
  {
    const double lo = 1.05, hi = 8.0;
    const int M = 128, D = 3;
    double ch[4] = {0, 0, 0, 0};
    for (int i = 0; i < M; ++i) {
      double th = M_PI * (i + 0.5) / M, u = cos(th);
      double x = 0.5 * ((hi + lo) + (hi - lo) * u);
      double f = 1.0 / x;
      for (int k = 0; k <= D; ++k) ch[k] += f * cos(k * th);
    }
    ch[0] /= M;
    for (int k = 1; k <= D; ++k) ch[k] *= 2.0 / M;
    double tm[4][4] = {{1, 0, 0, 0}, {0, 1, 0, 0}, {-1, 0, 2, 0}, {0, -3, 0, 4}};
    double au[4] = {0, 0, 0, 0};
    for (int k = 0; k <= D; ++k)
      for (int jj = 0; jj <= k; ++jj) au[jj] += ch[k] * tm[k][jj];
    double al = 2.0 / (hi - lo), be = -(hi + lo) / (hi - lo);
    double dx[4] = {0, 0, 0, 0};
    dx[0] += au[0];
    dx[0] += au[1] * be;           dx[1] += au[1] * al;
    dx[0] += au[2] * be * be;      dx[1] += au[2] * 2 * al * be;      dx[2] += au[2] * al * al;
    dx[0] += au[3] * be * be * be; dx[1] += au[3] * 3 * al * be * be; dx[2] += au[3] * 3 * al * al * be;
    dx[3] += au[3] * al * al * al;
    for (int k = 0; k < 4; ++k) cf.ic[k] = (float)dx[k];
  }
  {
    const double R = 0.860;
    const int D = 23, M = 256;
    double ch[24]; for (int k = 0; k < 24; ++k) ch[k] = 0;
    for (int i = 0; i < M; ++i) {
      double th = M_PI * (i + 0.5) / M, u = cos(th);
      double f = atanh(R * u);
      for (int k = 1; k <= D; k += 2) ch[k] += f * cos(k * th);
    }
    for (int k = 1; k <= D; k += 2) ch[k] *= 2.0 / M;
    static double tmn[24][24];
    memset(tmn, 0, sizeof(tmn));
    tmn[0][0] = 1; tmn[1][1] = 1;
    for (int k = 2; k <= D; ++k)
      for (int jj = 0; jj <= k; ++jj) {
        double v = -tmn[k - 2][jj];
        if (jj > 0) v += 2 * tmn[k - 1][jj - 1];
        tmn[k][jj] = v;
      }
    double am[24]; for (int jj = 0; jj < 24; ++jj) am[jj] = 0;
    for (int k = 1; k <= D; k += 2)
      for (int jj = 0; jj <= k; ++jj) am[jj] += ch[k] * tmn[k][jj];
    for (int m = 0; m < 12; ++m) cf.a[m] = (float)(am[2 * m + 1] / pow(R, 2 * m + 1));
  }
  return cf;
}

// ---------------------------------------------------------------------------
extern "C" void kernel_launch(void* const* d_in, const int* in_sizes, int n_in,
                              void* d_out, int out_size, void* d_ws, size_t ws_size,
                              hipStream_t stream) {
  (void)n_in; (void)out_size; (void)ws_size;
  const float* X = (const float*)d_in[0];
  const float* Wt = (const float*)d_in[1];
  float* out = (float*)d_out;
  float* ws = (float*)d_ws;
  const int nmat = in_sizes[0] / 1024;          // 32768
  const float inv_nmat = 1.0f / (float)nmat;

  Coef cf = make_coefs();

  k_zero<<<dim3(8), dim3(256), 0, stream>>>(ws);
  k_mean<<<dim3(1024), dim3(256), 0, stream>>>(X, ws, nmat, 256, inv_nmat);
  k_prep1<<<dim3(1), dim3(1024), 0, stream>>>(Wt, ws);
  k_log<<<dim3(1024), dim3(256), 0, stream>>>(X, ws, nmat, 4096, cf);
  k_prep2<<<dim3(1), dim3(1024), 0, stream>>>(ws, inv_nmat);
  k_final<<<dim3(2048), dim3(256), 0, stream>>>(X, ws, out, nmat, 8192);
}